// Round 4
// baseline (883.564 us; speedup 1.0000x reference)
//
#include <hip/hip_runtime.h>
#include <stdint.h>

// ---------------------------------------------------------------------------
// GAU forward on MI355X (gfx950), bf16 MFMA everywhere.
//   hid|qk = silu(x@[Wh|Wqk]+b) -> vT [2048][8192], gate [8192][2048],
//                                  q,k bf16 [8192][256] (cols 200..255 zero)
//   out2 = (relu(q@kT/32)^2 @ v) * gate   FUSED, no materialized attn (R11)
//   y    = (out2@Wo + bo) * x   fp32 [8192][1024]
//
// R11: fuse k_attn+k_pv into k_gau (flash-style; relu^2 attn has NO softmax
// so KV-tiling needs zero correction terms). R10 post-mortem: k_attn+k_pv
// together ~334 us, dominated by writing 128 MB attn then re-reading ~350 MB
// (FETCH_SIZE 350 MB, HBM 1.45 TB/s). Fused kernel:
//   - Block 64(M) x 1024(N-chunk), grid 256 = 1/CU (nc=id&1 uniform per
//     XCD -> vT panel + k resident per XCD L2; m_blk=id>>1).
//   - q-tile LDS-resident (28 KB swizzled); k,v streamed from L2/L3 as
//     B-frags (no LDS staging; 64B-line-exact coalescing; v frag reused 4x
//     in-register, n-cols disjoint per wave -> no cross-wave v duplication).
//   - Per KV-block j (128 rows): S=q@kT (28 MFMA/wave), P=relu^2(S/32)
//     -> bf16 -> swizzled LDS P dbuf (2x16 KB), ONE barrier, PV: acc+=P@v
//     (128 MFMA/wave). ~6000 cyc MFMA per barrier -> sync cost amortizes
//     5x better than k_pv's 1242.
//   - QK recomputed per N-chunk (2x): +35 GFLOP, vs ~480 MB saved HBM.
// k_hidqk / k_final / preps unchanged from R10. attnB + fullM fork gone.
// ---------------------------------------------------------------------------

typedef __bf16 bf16x8 __attribute__((ext_vector_type(8)));
typedef float f32x4 __attribute__((ext_vector_type(4)));

__device__ __forceinline__ uint16_t f2bf(float f) {
  uint32_t u = __builtin_bit_cast(uint32_t, f);
  u += 0x7fffu + ((u >> 16) & 1u);   // RNE; inputs are finite
  return (uint16_t)(u >> 16);
}
__device__ __forceinline__ float silu_f(float s) {
  return s / (1.f + __expf(-s));
}

__device__ __forceinline__ void gload16(const void* g, void* l) {
  __builtin_amdgcn_global_load_lds(
      (__attribute__((address_space(1))) void*)const_cast<void*>(g),
      (__attribute__((address_space(3))) void*)l, 16, 0, 0);
}

// ---------------- elementwise prep ----------------

__global__ void cast_to_bf16(const float* __restrict__ in, uint16_t* __restrict__ out, int n4) {
  int i = blockIdx.x * blockDim.x + threadIdx.x;
  if (i < n4) {
    float4 f = ((const float4*)in)[i];
    ushort4 o;
    o.x = f2bf(f.x); o.y = f2bf(f.y); o.z = f2bf(f.z); o.w = f2bf(f.w);
    ((ushort4*)out)[i] = o;
  }
}

// out[c][r] = (c < C) ? (bf16)in[r][c] : 0   ; out is [Cp][R]
__global__ void transpose_cast_pad(const float* __restrict__ in, uint16_t* __restrict__ out,
                                   int R, int C, int Cp) {
  __shared__ float tile[32][33];
  int cb = blockIdx.x * 32;
  int rb = blockIdx.y * 32;
  int tx = threadIdx.x;
  int ty = threadIdx.y;
#pragma unroll
  for (int i = 0; i < 4; ++i) {
    int r = rb + ty + i * 8;
    int c = cb + tx;
    tile[ty + i * 8][tx] = (c < C) ? in[(size_t)r * C + c] : 0.f;
  }
  __syncthreads();
#pragma unroll
  for (int i = 0; i < 4; ++i) {
    int c = cb + ty + i * 8;
    if (c < Cp) out[(size_t)c * R + rb + tx] = f2bf(tile[tx][ty + i * 8]);
  }
}

// ---------------- params ----------------

struct EpiParams {
  const float* bias;
  const float* bias2;
  const float* g0;
  const float* b0;
  const float* g1;
  const float* b1;
  const uint16_t* gate;
  const float* x;
  uint16_t* o16a;
  uint16_t* o16b;
  uint16_t* oq;
  uint16_t* ok;
  float* o32;
};

// ---------------------------------------------------------------------------
// Shared 128x128 ring-4 K-loop (4 waves, BK=32, 64 KB LDS, 2 blocks/CU).
// ---------------------------------------------------------------------------
#define TILE128(T_, B_, BS_)                                                   \
  do {                                                                         \
    const uint16_t* base_ = SH + (B_) * 8192;                                  \
    const int kp_ = (((T_) + 3) & (NT - 1)) * 32;                              \
    uint16_t* sd_ = SH + (BS_) * 8192 + wave * 512;                            \
    gload16(gA0 + kp_, sd_);                                                   \
    gload16(gA1 + kp_, sd_ + 2048);                                            \
    gload16(gB0 + kp_, sd_ + 4096);                                            \
    gload16(gB1 + kp_, sd_ + 6144);                                            \
    bf16x8 a_[4], b_[4];                                                       \
    _Pragma("unroll") for (int j = 0; j < 4; ++j)                              \
        b_[j] = *(const bf16x8*)(base_ + rdB + j * 512);                       \
    _Pragma("unroll") for (int i = 0; i < 4; ++i)                              \
        a_[i] = *(const bf16x8*)(base_ + rdA + i * 512);                       \
    __builtin_amdgcn_s_setprio(1);                                             \
    _Pragma("unroll") for (int i = 0; i < 4; ++i)                              \
      _Pragma("unroll") for (int j = 0; j < 4; ++j)                            \
          acc[i][j] = __builtin_amdgcn_mfma_f32_16x16x32_bf16(                 \
              a_[i], b_[j], acc[i][j], 0, 0, 0);                               \
    __builtin_amdgcn_s_setprio(0);                                             \
    asm volatile("s_waitcnt vmcnt(8)" ::: "memory");                           \
    __builtin_amdgcn_sched_barrier(0);                                         \
    __builtin_amdgcn_s_barrier();                                              \
    __builtin_amdgcn_sched_barrier(0);                                         \
  } while (0)

#define RING_LOOP128()                                                         \
  do {                                                                         \
    _Pragma("unroll") for (int s_ = 0; s_ < 3; ++s_) {                         \
      uint16_t* d_ = SH + s_ * 8192 + wave * 512;                              \
      gload16(gA0 + s_ * 32, d_);                                              \
      gload16(gA1 + s_ * 32, d_ + 2048);                                       \
      gload16(gB0 + s_ * 32, d_ + 4096);                                       \
      gload16(gB1 + s_ * 32, d_ + 6144);                                       \
    }                                                                          \
    asm volatile("s_waitcnt vmcnt(8)" ::: "memory");                           \
    __builtin_amdgcn_sched_barrier(0);                                         \
    __builtin_amdgcn_s_barrier();                                              \
    __builtin_amdgcn_sched_barrier(0);                                         \
    for (int t0_ = 0; t0_ < NT; t0_ += 4) {                                    \
      TILE128(t0_ + 0, 0, 3);                                                  \
      TILE128(t0_ + 1, 1, 0);                                                  \
      TILE128(t0_ + 2, 2, 1);                                                  \
      TILE128(t0_ + 3, 3, 2);                                                  \
    }                                                                          \
    asm volatile("s_waitcnt vmcnt(0)" ::: "memory");                           \
    __builtin_amdgcn_sched_barrier(0);                                         \
    __syncthreads();                                                           \
  } while (0)

// ---------------------------------------------------------------------------
// k_hidqk: C = xb[8192,1024] @ [WhT;WqkT][4352,1024]^T, 128x128 tile.
// ---------------------------------------------------------------------------
__global__ __launch_bounds__(256, 2) void k_hidqk(
    const uint16_t* __restrict__ A, const uint16_t* __restrict__ Bt, EpiParams p) {
  __shared__ __align__(16) uint16_t SH[32768];   // 4 ring slots x (A|B), 64 KB

  const int tid = threadIdx.x;
  const int lane = tid & 63;
  const int wave = tid >> 6;
  const int wr = (wave >> 1) * 64;
  const int wc = (wave & 1) * 64;
  const int m0 = blockIdx.y * 128;
  const int n0 = blockIdx.x * 128;
  const int lda = 1024, ldb = 1024;
  const int NT = 32;   // K=1024

  f32x4 acc[4][4] = {};

  const int fr = lane & 15;
  const int rg = lane >> 4;
  const int swz = (rg ^ ((fr >> 1) & 3)) * 8;
  const int rdA = (wr + fr) * 32 + swz;
  const int rdB = 4096 + (wc + fr) * 32 + swz;

  const int srow = lane >> 2;
  const int sk = ((lane & 3) ^ ((lane >> 3) & 3)) * 8;
  const uint16_t* gA0 = A + (size_t)(m0 + wave * 16 + srow) * lda + sk;
  const uint16_t* gA1 = gA0 + (size_t)64 * lda;
  const uint16_t* gB0 = Bt + (size_t)(n0 + wave * 16 + srow) * ldb + sk;
  const uint16_t* gB1 = gB0 + (size_t)64 * ldb;

  RING_LOOP128();

  // C/D layout: col = lane&15, row = rg*4 + reg   [m89-verified]
  if (n0 < 2048) {
    // vT (transposed store). Arena [16 n-rows][64 m + pad] stride 72.
    uint16_t* ar = SH + wave * 2048;
    const int lrow = lane >> 3;
    const int mc = (lane & 7) * 8;
#pragma unroll
    for (int j = 0; j < 4; ++j) {
      const float bc = p.bias[n0 + wc + j * 16 + fr];
#pragma unroll
      for (int i = 0; i < 4; ++i)
#pragma unroll
        for (int r = 0; r < 4; ++r)
          ar[fr * 72 + i * 16 + rg * 4 + r] = f2bf(silu_f(acc[i][j][r] + bc));
#pragma unroll
      for (int rr = 0; rr < 2; ++rr) {
        bf16x8 v = *(const bf16x8*)(ar + (rr * 8 + lrow) * 72 + mc);
        *(bf16x8*)(p.o16a + (size_t)(n0 + wc + j * 16 + rr * 8 + lrow) * 8192 + m0 + wr + mc) = v;
      }
    }
  } else if (n0 < 4096) {
    // gate. Arena [16 m-rows][64 n + pad] stride 72.
    uint16_t* ar = SH + wave * 2048;
    const int lrow = lane >> 3;
    const int nc = (lane & 7) * 8;
    float bc[4];
#pragma unroll
    for (int j = 0; j < 4; ++j) bc[j] = p.bias[n0 + wc + j * 16 + fr];
#pragma unroll
    for (int i = 0; i < 4; ++i) {
#pragma unroll
      for (int j = 0; j < 4; ++j)
#pragma unroll
        for (int r = 0; r < 4; ++r)
          ar[(rg * 4 + r) * 72 + j * 16 + fr] = f2bf(silu_f(acc[i][j][r] + bc[j]));
#pragma unroll
      for (int rr = 0; rr < 2; ++rr) {
        bf16x8 v = *(const bf16x8*)(ar + (rr * 8 + lrow) * 72 + nc);
        *(bf16x8*)(p.o16b + (size_t)(m0 + wr + i * 16 + rr * 8 + lrow) * 2048 + (n0 - 2048) + wc + nc) = v;
      }
    }
  } else {
    // q,k: stride 256, cols 200..255 forced zero.
#pragma unroll
    for (int i = 0; i < 4; ++i) {
#pragma unroll
      for (int j = 0; j < 4; ++j) {
        const int row = m0 + wr + i * 16 + rg * 4;
        const int qc = n0 + wc + j * 16 + fr - 4096;   // 0..255
#pragma unroll
        for (int r = 0; r < 4; ++r) {
          float qv = 0.f, kv = 0.f;
          if (qc < 200) {
            float s = silu_f(acc[i][j][r] + p.bias2[qc]);
            qv = s * p.g0[qc] + p.b0[qc];
            kv = s * p.g1[qc] + p.b1[qc];
          }
          p.oq[(size_t)(row + r) * 256 + qc] = f2bf(qv);
          p.ok[(size_t)(row + r) * 256 + qc] = f2bf(kv);
        }
      }
    }
  }
}

// ---------------------------------------------------------------------------
// k_gau: out2 = (relu(q@kT/32)^2 @ v) * gate, fused flash-style (no softmax,
// no correction terms). Block = 64(M) x 1024(N-chunk), 512 thr, 8 waves
// (each wave: S cols w*16..+16, out2 cols w*128..+128). Per KV-block j of
// 128: S (K=224, q from LDS, k streamed) -> P relu^2 bf16 -> swizzled LDS
// dbuf -> ONE barrier -> PV (v streamed from vT). q LDS [7][64][32]
// swizzled; P [4][64][32] swizzled, same scheme as the GEMM tiles.
// ---------------------------------------------------------------------------
__global__ __launch_bounds__(512, 2) void k_gau(
    const uint16_t* __restrict__ Qg,
    const uint16_t* __restrict__ Kg,
    const uint16_t* __restrict__ Vt,
    const uint16_t* __restrict__ gate,
    uint16_t* __restrict__ out2) {
  __shared__ __align__(16) uint16_t SH[30720];  // Qs 28KB | P dbuf 2x16KB

  const int id = blockIdx.x;
  const int nch = id & 1;        // N-chunk: uniform per XCD (id%8 parity)
  const int mb = id >> 1;
  const int m0 = mb * 64;
  const int n0 = nch * 1024;

  const int tid = threadIdx.x;
  const int lane = tid & 63;
  const int w = tid >> 6;
  const int fr = lane & 15;
  const int rg = lane >> 4;
  const int swz = (rg ^ ((fr >> 1) & 3)) * 8;

  // stage Qs once: rows m0..m0+64 x qk 0..224, layout [s][64][32] swizzled
  {
    const int srow = lane >> 2;
    const int sk = ((lane & 3) ^ ((lane >> 3) & 3)) * 8;
    for (int t = w; t < 28; t += 8) {
      const int s = t >> 2, wg = t & 3;
      gload16(Qg + (size_t)(m0 + wg * 16 + srow) * 256 + s * 32 + sk,
              SH + s * 2048 + wg * 512);
    }
  }
  asm volatile("s_waitcnt vmcnt(0)" ::: "memory");
  __syncthreads();

  f32x4 acc[4][8] = {};

  const uint16_t* kbase = Kg + (size_t)(w * 16 + fr) * 256 + rg * 8;
  const uint16_t* vbase = Vt + (size_t)(n0 + w * 128 + fr) * 8192 + rg * 8;
  const int plo = (w & 1) * 2 + (fr >> 3);   // logical 16B-slot of P-write
  const int pkq = (w >> 1) * 2048;           // P k-step region for this wave

#pragma unroll 1
  for (int j = 0; j < 64; ++j) {
    const int j0 = j * 128;
    uint16_t* Pb = SH + 14336 + (j & 1) * 8192;

    // S = q @ k^T  (K=224; k-frags streamed from L2)
    f32x4 sacc[4] = {};
#pragma unroll
    for (int s = 0; s < 7; ++s) {
      bf16x8 kb = *(const bf16x8*)(kbase + (size_t)j0 * 256 + s * 32);
#pragma unroll
      for (int i = 0; i < 4; ++i) {
        bf16x8 qa = *(const bf16x8*)(SH + s * 2048 + (i * 16 + fr) * 32 + swz);
        sacc[i] = __builtin_amdgcn_mfma_f32_16x16x32_bf16(qa, kb, sacc[i], 0, 0, 0);
      }
    }
    // P = relu(S/32)^2 -> bf16 -> swizzled LDS (A-operand layout for PV)
#pragma unroll
    for (int i = 0; i < 4; ++i)
#pragma unroll
      for (int r = 0; r < 4; ++r) {
        const int m = i * 16 + rg * 4 + r;
        float sv = fmaxf(sacc[i][r] * 0.03125f, 0.f);
        Pb[pkq + m * 32 + ((plo ^ ((m >> 1) & 3)) * 8) + (fr & 7)] = f2bf(sv * sv);
      }
    __syncthreads();   // P visible; WAR on Pb^1 separated by next j's barrier

    // PV: acc += P @ v   (v-frags streamed from vT; 4x in-reg reuse)
#pragma unroll
    for (int ks = 0; ks < 4; ++ks) {
      bf16x8 pa[4];
#pragma unroll
      for (int i = 0; i < 4; ++i)
        pa[i] = *(const bf16x8*)(Pb + ks * 2048 + (i * 16 + fr) * 32 + swz);
#pragma unroll
      for (int jh = 0; jh < 2; ++jh) {
        bf16x8 vb[4];
#pragma unroll
        for (int jj = 0; jj < 4; ++jj)
          vb[jj] = *(const bf16x8*)(vbase + (size_t)(jh * 64 + jj * 16) * 8192 + j0 + ks * 32);
        __builtin_amdgcn_s_setprio(1);
#pragma unroll
        for (int i = 0; i < 4; ++i)
#pragma unroll
          for (int jj = 0; jj < 4; ++jj)
            acc[i][jh * 4 + jj] = __builtin_amdgcn_mfma_f32_16x16x32_bf16(
                pa[i], vb[jj], acc[i][jh * 4 + jj], 0, 0, 0);
        __builtin_amdgcn_s_setprio(0);
      }
    }
  }
  __syncthreads();   // all waves done with Qs/P before arena reuse

  // epilogue: per-wave [16][72] arena bounce, gate mult, 16B stores
  uint16_t* ar = SH + w * 3840;
  const int lrow = lane >> 3;
  const int nc8 = (lane & 7) * 8;
#pragma unroll
  for (int i = 0; i < 4; ++i)
#pragma unroll
    for (int h = 0; h < 2; ++h) {
#pragma unroll
      for (int jj = 0; jj < 4; ++jj)
#pragma unroll
        for (int r = 0; r < 4; ++r)
          ar[(rg * 4 + r) * 72 + jj * 16 + fr] = f2bf(acc[i][h * 4 + jj][r]);
#pragma unroll
      for (int rr = 0; rr < 2; ++rr) {
        const size_t base = (size_t)(m0 + i * 16 + rr * 8 + lrow) * 2048 + n0 + w * 128 + h * 64 + nc8;
        bf16x8 v = *(const bf16x8*)(ar + (rr * 8 + lrow) * 72 + nc8);
        bf16x8 g = *(const bf16x8*)(gate + base);
        bf16x8 o;
#pragma unroll
        for (int e = 0; e < 8; ++e) o[e] = (__bf16)((float)v[e] * (float)g[e]);
        *(bf16x8*)(out2 + base) = o;
      }
    }
}

// ---------------------------------------------------------------------------
// k_final: y = (out2g@WoT^T + bo) * x, fp32 out. 128x128, K=2048, ring-4.
// ---------------------------------------------------------------------------
__global__ __launch_bounds__(256, 2) void k_final(
    const uint16_t* __restrict__ A,
    const uint16_t* __restrict__ Bt, EpiParams p) {
  __shared__ __align__(16) uint16_t SH[32768];

  const int tid = threadIdx.x;
  const int lane = tid & 63;
  const int wave = tid >> 6;
  const int wr = (wave >> 1) * 64;
  const int wc = (wave & 1) * 64;
  const int m0 = blockIdx.y * 128;
  const int n0 = blockIdx.x * 128;
  const int lda = 2048, ldb = 2048;
  const int NT = 64;   // K=2048

  f32x4 acc[4][4] = {};

  const int fr = lane & 15;
  const int rg = lane >> 4;
  const int swz = (rg ^ ((fr >> 1) & 3)) * 8;
  const int rdA = (wr + fr) * 32 + swz;
  const int rdB = 4096 + (wc + fr) * 32 + swz;

  const int srow = lane >> 2;
  const int sk = ((lane & 3) ^ ((lane >> 3) & 3)) * 8;
  const uint16_t* gA0 = A + (size_t)(m0 + wave * 16 + srow) * lda + sk;
  const uint16_t* gA1 = gA0 + (size_t)64 * lda;
  const uint16_t* gB0 = Bt + (size_t)(n0 + wave * 16 + srow) * ldb + sk;
  const uint16_t* gB1 = gB0 + (size_t)64 * ldb;

  RING_LOOP128();

#pragma unroll
  for (int i = 0; i < 4; ++i) {
#pragma unroll
    for (int j = 0; j < 4; ++j) {
      const int row = m0 + wr + i * 16 + rg * 4;
      const int col = n0 + wc + j * 16 + fr;
      const float bc = p.bias[col];
#pragma unroll
      for (int r = 0; r < 4; ++r) {
        size_t idx = (size_t)(row + r) * 1024 + col;
        p.o32[idx] = (acc[i][j][r] + bc) * p.x[idx];
      }
    }
  }
}

// ---------------- launch ----------------

extern "C" void kernel_launch(void* const* d_in, const int* in_sizes, int n_in,
                              void* d_out, int out_size, void* d_ws, size_t ws_size,
                              hipStream_t stream) {
  const float* x        = (const float*)d_in[0];
  const float* W_hidden = (const float*)d_in[1];
  const float* b_hidden = (const float*)d_in[2];
  const float* W_qk     = (const float*)d_in[3];
  const float* b_qk     = (const float*)d_in[4];
  const float* gamma    = (const float*)d_in[5];
  const float* beta     = (const float*)d_in[6];
  const float* W_out    = (const float*)d_in[7];
  const float* b_out    = (const float*)d_in[8];
  float* out = (float*)d_out;

  char* base = (char*)d_ws;
  uint16_t* xb    = (uint16_t*)(base);                         // 16 MB  [8192][1024]
  uint16_t* WhT   = (uint16_t*)(base + (16ull << 20));         //  8 MB  [4096][1024]
  uint16_t* WqkT  = (uint16_t*)(base + (24ull << 20));         // .5 MB  [256][1024]
  uint16_t* WoT   = (uint16_t*)(base + (25ull << 20));         //  4 MB  [1024][2048]
  uint16_t* q     = (uint16_t*)(base + (29ull << 20));         //  4 MB  [8192][256]
  uint16_t* kk    = (uint16_t*)(base + (33ull << 20));         //  4 MB
  uint16_t* vT    = (uint16_t*)(base + (37ull << 20));         // 32 MB  [2048][8192]
  uint16_t* gate  = (uint16_t*)(base + (69ull << 20));         // 32 MB  [8192][2048]
  uint16_t* out2g = (uint16_t*)(base + (101ull << 20));        // 32 MB  [8192][2048]
  (void)in_sizes; (void)n_in; (void)out_size; (void)ws_size;

  // prep
  cast_to_bf16<<<(8192 * 1024 / 4) / 256, 256, 0, stream>>>(x, xb, 8192 * 1024 / 4);
  transpose_cast_pad<<<dim3(4096 / 32, 1024 / 32), dim3(32, 8), 0, stream>>>(W_hidden, WhT, 1024, 4096, 4096);
  transpose_cast_pad<<<dim3(256 / 32, 1024 / 32), dim3(32, 8), 0, stream>>>(W_qk, WqkT, 1024, 200, 256);
  transpose_cast_pad<<<dim3(1024 / 32, 2048 / 32), dim3(32, 8), 0, stream>>>(W_out, WoT, 2048, 1024, 1024);

  // fused hid + qk   (N = 4096 + 256 = 4352)
  {
    EpiParams p{};
    p.bias = b_hidden; p.bias2 = b_qk;
    p.g0 = gamma; p.b0 = beta; p.g1 = gamma + 200; p.b1 = beta + 200;
    p.o16a = vT; p.o16b = gate; p.oq = q; p.ok = kk;
    k_hidqk<<<dim3(34, 64), 256, 0, stream>>>(xb, WhT, p);
  }

  // fused attention: out2g = (relu(q@kT/32)^2 @ v) * gate
  k_gau<<<dim3(256), 512, 0, stream>>>(q, kk, vT, gate, out2g);

  // y = (out2g@Wo + bo) * x
  {
    EpiParams p{};
    p.bias = b_out; p.x = x; p.o32 = out;
    k_final<<<dim3(8, 64), 256, 0, stream>>>(out2g, WoT, p);
  }
}

// Round 5
// 653.456 us; speedup vs baseline: 1.3521x; 1.3521x over previous
//
#include <hip/hip_runtime.h>
#include <stdint.h>

// ---------------------------------------------------------------------------
// GAU forward on MI355X (gfx950), bf16 MFMA everywhere.
//   hid|qk = silu(x@[Wh|Wqk]+b) -> vT [2048][8192], gate [8192][2048],
//                                  q,k bf16 [8192][256] (cols 200..255 zero)
//   attn = relu(q@kT / 32)^2    bf16, 2 stripes of 4096 rows (64 MB buffer)
//   out2 = (attn@v) * gate      bf16, split-K k_pv + k_sum
//   y    = (out2@Wo + bo) * x   fp32, per-stripe k_final
//
// R12: revert R11 fusion (latency/L3-bound: 657 us, MfmaUtil 21%). Fix the
// real problem instead: the 2-stripe path ran k_pv on 128 blocks = HALF the
// machine idle for 2x222 us. Split-K over kv: kh in {0,1}, K=4096/block,
// grid 16m x 8n x 2kh = 256 blocks = 1/CU, K-loop engine byte-identical to
// R9 (ring-4, 32 MFMA/barrier, vmcnt(8)). Raw bf16 partials go to the TWO
// HALVES of out2g (other stripe's half is dead then; ping-pong verified:
// s0 -> {0,+16M}, final(s0) consumes before pv(s1) overwrites; s1 -> {+16M,0}).
// k_sum does (P0+P1)*gate in-place; k_final runs per stripe (grid 8x32,
// rows-only dependence). Gate leaves k_pv (-16 MB fetch). Mapping bx=id&7
// pins one vT panel per XCD (L2-resident); attn streams via L3, latency
// hidden by the ring's ~2-tile prefetch window.
// ---------------------------------------------------------------------------

typedef __bf16 bf16x8 __attribute__((ext_vector_type(8)));
typedef float f32x4 __attribute__((ext_vector_type(4)));

__device__ __forceinline__ uint16_t f2bf(float f) {
  uint32_t u = __builtin_bit_cast(uint32_t, f);
  u += 0x7fffu + ((u >> 16) & 1u);   // RNE; inputs are finite
  return (uint16_t)(u >> 16);
}
__device__ __forceinline__ float silu_f(float s) {
  return s / (1.f + __expf(-s));
}

__device__ __forceinline__ void gload16(const void* g, void* l) {
  __builtin_amdgcn_global_load_lds(
      (__attribute__((address_space(1))) void*)const_cast<void*>(g),
      (__attribute__((address_space(3))) void*)l, 16, 0, 0);
}

// ---------------- elementwise prep ----------------

__global__ void cast_to_bf16(const float* __restrict__ in, uint16_t* __restrict__ out, int n4) {
  int i = blockIdx.x * blockDim.x + threadIdx.x;
  if (i < n4) {
    float4 f = ((const float4*)in)[i];
    ushort4 o;
    o.x = f2bf(f.x); o.y = f2bf(f.y); o.z = f2bf(f.z); o.w = f2bf(f.w);
    ((ushort4*)out)[i] = o;
  }
}

// out[c][r] = (c < C) ? (bf16)in[r][c] : 0   ; out is [Cp][R]
__global__ void transpose_cast_pad(const float* __restrict__ in, uint16_t* __restrict__ out,
                                   int R, int C, int Cp) {
  __shared__ float tile[32][33];
  int cb = blockIdx.x * 32;
  int rb = blockIdx.y * 32;
  int tx = threadIdx.x;
  int ty = threadIdx.y;
#pragma unroll
  for (int i = 0; i < 4; ++i) {
    int r = rb + ty + i * 8;
    int c = cb + tx;
    tile[ty + i * 8][tx] = (c < C) ? in[(size_t)r * C + c] : 0.f;
  }
  __syncthreads();
#pragma unroll
  for (int i = 0; i < 4; ++i) {
    int c = cb + ty + i * 8;
    if (c < Cp) out[(size_t)c * R + rb + tx] = f2bf(tile[tx][ty + i * 8]);
  }
}

// k_sum: P0 = (P0 + P1) * gate, elementwise bf16x8, in-place on P0.
__global__ void k_sum(uint16_t* __restrict__ P0, const uint16_t* __restrict__ P1,
                      const uint16_t* __restrict__ g, int n8) {
  int i = blockIdx.x * blockDim.x + threadIdx.x;
  if (i < n8) {
    bf16x8 a = ((const bf16x8*)P0)[i];
    bf16x8 b = ((const bf16x8*)P1)[i];
    bf16x8 gg = ((const bf16x8*)g)[i];
    bf16x8 o;
#pragma unroll
    for (int e = 0; e < 8; ++e)
      o[e] = (__bf16)(((float)a[e] + (float)b[e]) * (float)gg[e]);
    ((bf16x8*)P0)[i] = o;
  }
}

// ---------------- params ----------------

struct EpiParams {
  const float* bias;
  const float* bias2;
  const float* g0;
  const float* b0;
  const float* g1;
  const float* b1;
  const uint16_t* gate;
  const float* x;
  uint16_t* o16a;
  uint16_t* o16b;
  uint16_t* oq;
  uint16_t* ok;
  float* o32;
};

// ---------------------------------------------------------------------------
// Shared 128x128 ring-4 K-loop (4 waves, BK=32, 64 KB LDS, 2 blocks/CU).
// ---------------------------------------------------------------------------
#define TILE128(T_, B_, BS_)                                                   \
  do {                                                                         \
    const uint16_t* base_ = SH + (B_) * 8192;                                  \
    const int kp_ = (((T_) + 3) & (NT - 1)) * 32;                              \
    uint16_t* sd_ = SH + (BS_) * 8192 + wave * 512;                            \
    gload16(gA0 + kp_, sd_);                                                   \
    gload16(gA1 + kp_, sd_ + 2048);                                            \
    gload16(gB0 + kp_, sd_ + 4096);                                            \
    gload16(gB1 + kp_, sd_ + 6144);                                            \
    bf16x8 a_[4], b_[4];                                                       \
    _Pragma("unroll") for (int j = 0; j < 4; ++j)                              \
        b_[j] = *(const bf16x8*)(base_ + rdB + j * 512);                       \
    _Pragma("unroll") for (int i = 0; i < 4; ++i)                              \
        a_[i] = *(const bf16x8*)(base_ + rdA + i * 512);                       \
    __builtin_amdgcn_s_setprio(1);                                             \
    _Pragma("unroll") for (int i = 0; i < 4; ++i)                              \
      _Pragma("unroll") for (int j = 0; j < 4; ++j)                            \
          acc[i][j] = __builtin_amdgcn_mfma_f32_16x16x32_bf16(                 \
              a_[i], b_[j], acc[i][j], 0, 0, 0);                               \
    __builtin_amdgcn_s_setprio(0);                                             \
    asm volatile("s_waitcnt vmcnt(8)" ::: "memory");                           \
    __builtin_amdgcn_sched_barrier(0);                                         \
    __builtin_amdgcn_s_barrier();                                              \
    __builtin_amdgcn_sched_barrier(0);                                         \
  } while (0)

#define RING_LOOP128()                                                         \
  do {                                                                         \
    _Pragma("unroll") for (int s_ = 0; s_ < 3; ++s_) {                         \
      uint16_t* d_ = SH + s_ * 8192 + wave * 512;                              \
      gload16(gA0 + s_ * 32, d_);                                              \
      gload16(gA1 + s_ * 32, d_ + 2048);                                       \
      gload16(gB0 + s_ * 32, d_ + 4096);                                       \
      gload16(gB1 + s_ * 32, d_ + 6144);                                       \
    }                                                                          \
    asm volatile("s_waitcnt vmcnt(8)" ::: "memory");                           \
    __builtin_amdgcn_sched_barrier(0);                                         \
    __builtin_amdgcn_s_barrier();                                              \
    __builtin_amdgcn_sched_barrier(0);                                         \
    for (int t0_ = 0; t0_ < NT; t0_ += 4) {                                    \
      TILE128(t0_ + 0, 0, 3);                                                  \
      TILE128(t0_ + 1, 1, 0);                                                  \
      TILE128(t0_ + 2, 2, 1);                                                  \
      TILE128(t0_ + 3, 3, 2);                                                  \
    }                                                                          \
    asm volatile("s_waitcnt vmcnt(0)" ::: "memory");                           \
    __builtin_amdgcn_sched_barrier(0);                                         \
    __syncthreads();                                                           \
  } while (0)

// ---------------------------------------------------------------------------
// k_hidqk: C = xb[8192,1024] @ [WhT;WqkT][4352,1024]^T, 128x128 tile.
// ---------------------------------------------------------------------------
__global__ __launch_bounds__(256, 2) void k_hidqk(
    const uint16_t* __restrict__ A, const uint16_t* __restrict__ Bt, EpiParams p) {
  __shared__ __align__(16) uint16_t SH[32768];   // 4 ring slots x (A|B), 64 KB

  const int tid = threadIdx.x;
  const int lane = tid & 63;
  const int wave = tid >> 6;
  const int wr = (wave >> 1) * 64;
  const int wc = (wave & 1) * 64;
  const int m0 = blockIdx.y * 128;
  const int n0 = blockIdx.x * 128;
  const int lda = 1024, ldb = 1024;
  const int NT = 32;   // K=1024

  f32x4 acc[4][4] = {};

  const int fr = lane & 15;
  const int rg = lane >> 4;
  const int swz = (rg ^ ((fr >> 1) & 3)) * 8;
  const int rdA = (wr + fr) * 32 + swz;
  const int rdB = 4096 + (wc + fr) * 32 + swz;

  const int srow = lane >> 2;
  const int sk = ((lane & 3) ^ ((lane >> 3) & 3)) * 8;
  const uint16_t* gA0 = A + (size_t)(m0 + wave * 16 + srow) * lda + sk;
  const uint16_t* gA1 = gA0 + (size_t)64 * lda;
  const uint16_t* gB0 = Bt + (size_t)(n0 + wave * 16 + srow) * ldb + sk;
  const uint16_t* gB1 = gB0 + (size_t)64 * ldb;

  RING_LOOP128();

  // C/D layout: col = lane&15, row = rg*4 + reg   [m89-verified]
  if (n0 < 2048) {
    // vT (transposed store). Arena [16 n-rows][64 m + pad] stride 72.
    uint16_t* ar = SH + wave * 2048;
    const int lrow = lane >> 3;
    const int mc = (lane & 7) * 8;
#pragma unroll
    for (int j = 0; j < 4; ++j) {
      const float bc = p.bias[n0 + wc + j * 16 + fr];
#pragma unroll
      for (int i = 0; i < 4; ++i)
#pragma unroll
        for (int r = 0; r < 4; ++r)
          ar[fr * 72 + i * 16 + rg * 4 + r] = f2bf(silu_f(acc[i][j][r] + bc));
#pragma unroll
      for (int rr = 0; rr < 2; ++rr) {
        bf16x8 v = *(const bf16x8*)(ar + (rr * 8 + lrow) * 72 + mc);
        *(bf16x8*)(p.o16a + (size_t)(n0 + wc + j * 16 + rr * 8 + lrow) * 8192 + m0 + wr + mc) = v;
      }
    }
  } else if (n0 < 4096) {
    // gate. Arena [16 m-rows][64 n + pad] stride 72.
    uint16_t* ar = SH + wave * 2048;
    const int lrow = lane >> 3;
    const int nc = (lane & 7) * 8;
    float bc[4];
#pragma unroll
    for (int j = 0; j < 4; ++j) bc[j] = p.bias[n0 + wc + j * 16 + fr];
#pragma unroll
    for (int i = 0; i < 4; ++i) {
#pragma unroll
      for (int j = 0; j < 4; ++j)
#pragma unroll
        for (int r = 0; r < 4; ++r)
          ar[(rg * 4 + r) * 72 + j * 16 + fr] = f2bf(silu_f(acc[i][j][r] + bc[j]));
#pragma unroll
      for (int rr = 0; rr < 2; ++rr) {
        bf16x8 v = *(const bf16x8*)(ar + (rr * 8 + lrow) * 72 + nc);
        *(bf16x8*)(p.o16b + (size_t)(m0 + wr + i * 16 + rr * 8 + lrow) * 2048 + (n0 - 2048) + wc + nc) = v;
      }
    }
  } else {
    // q,k: stride 256, cols 200..255 forced zero.
#pragma unroll
    for (int i = 0; i < 4; ++i) {
#pragma unroll
      for (int j = 0; j < 4; ++j) {
        const int row = m0 + wr + i * 16 + rg * 4;
        const int qc = n0 + wc + j * 16 + fr - 4096;   // 0..255
#pragma unroll
        for (int r = 0; r < 4; ++r) {
          float qv = 0.f, kv = 0.f;
          if (qc < 200) {
            float s = silu_f(acc[i][j][r] + p.bias2[qc]);
            qv = s * p.g0[qc] + p.b0[qc];
            kv = s * p.g1[qc] + p.b1[qc];
          }
          p.oq[(size_t)(row + r) * 256 + qc] = f2bf(qv);
          p.ok[(size_t)(row + r) * 256 + qc] = f2bf(kv);
        }
      }
    }
  }
}

// ---------------------------------------------------------------------------
// k_attn: attn = relu(q@kT/32)^2, K=256 (padded), 128x128 tile, ring-4.
// ---------------------------------------------------------------------------
__global__ __launch_bounds__(256, 2) void k_attn(
    const uint16_t* __restrict__ Q,
    const uint16_t* __restrict__ Kt,
    uint16_t* __restrict__ attn) {
  __shared__ __align__(16) uint16_t SH[32768];

  const int tid = threadIdx.x;
  const int lane = tid & 63;
  const int wave = tid >> 6;
  const int wr = (wave >> 1) * 64;
  const int wc = (wave & 1) * 64;
  const int m0 = blockIdx.y * 128;
  const int n0 = blockIdx.x * 128;
  const int lda = 256, ldb = 256;
  const int NT = 8;   // K=256

  f32x4 acc[4][4] = {};

  const int fr = lane & 15;
  const int rg = lane >> 4;
  const int swz = (rg ^ ((fr >> 1) & 3)) * 8;
  const int rdA = (wr + fr) * 32 + swz;
  const int rdB = 4096 + (wc + fr) * 32 + swz;

  const int srow = lane >> 2;
  const int sk = ((lane & 3) ^ ((lane >> 3) & 3)) * 8;
  const uint16_t* gA0 = Q + (size_t)(m0 + wave * 16 + srow) * lda + sk;
  const uint16_t* gA1 = gA0 + (size_t)64 * lda;
  const uint16_t* gB0 = Kt + (size_t)(n0 + wave * 16 + srow) * ldb + sk;
  const uint16_t* gB1 = gB0 + (size_t)64 * ldb;

  RING_LOOP128();

  // bounce epilogue: per i, wave-local [16 rows][64 cols] stride 72, dbuf
#pragma unroll
  for (int i = 0; i < 4; ++i) {
    uint16_t* sl = SH + wave * 4096 + (i & 1) * 2048;
#pragma unroll
    for (int j = 0; j < 4; ++j)
#pragma unroll
      for (int r = 0; r < 4; ++r) {
        float s = fmaxf(acc[i][j][r] * 0.03125f, 0.f);
        sl[(rg * 4 + r) * 72 + j * 16 + fr] = f2bf(s * s);
      }
    const int row = lane >> 2;
    const int c0 = (lane & 3) * 16;
    bf16x8 v0 = *(const bf16x8*)(sl + row * 72 + c0);
    bf16x8 v1 = *(const bf16x8*)(sl + row * 72 + c0 + 8);
    uint16_t* dst = attn + (size_t)(m0 + wr + i * 16 + row) * 8192 + (n0 + wc + c0);
    *(bf16x8*)(dst) = v0;
    *(bf16x8*)(dst + 8) = v1;
  }
}

// ---------------------------------------------------------------------------
// k_pv: split-K partials. attn stripe [4096][8192] @ vT^T -> P_kh [4096][2048]
// raw bf16 (no gate). 256x256 tile, kh = kv-half, K=4096/block, grid
// 16m x 8n x 2kh = 256 blocks = 1/CU. Engine = R9 ring-4, 32 MFMA/barrier,
// vmcnt(8). Mapping: bx = id&7 (one vT panel per XCD, L2-resident),
// kh = (id>>3)&1, by = id>>4.
// ---------------------------------------------------------------------------
__global__ __launch_bounds__(512, 2) void k_pv(
    const uint16_t* __restrict__ A,
    const uint16_t* __restrict__ Bt,
    uint16_t* __restrict__ P0,
    uint16_t* __restrict__ P1) {
  __shared__ __align__(16) uint16_t SH[65536];   // 4 x (A 16KB | B 16KB) = 128 KB

  const int id = blockIdx.x;
  const int bx = id & 7;
  const int kh = (id >> 3) & 1;
  const int by = id >> 4;
  const int m0 = by * 256;
  const int n0 = bx * 256;
  const int kv0 = kh * 4096;

  const int tid = threadIdx.x;
  const int lane = tid & 63;
  const int wave = tid >> 6;
  const int wrM = (wave >> 2) * 128;   // wave M origin (0/128)
  const int wcN = (wave & 3) * 64;     // wave N origin (0/64/128/192)

  const int fr = lane & 15;
  const int rg = lane >> 4;
  const int swz = (rg ^ ((fr >> 1) & 3)) * 8;

  const int rdA = (wrM + fr) * 32 + swz;          // + buf*16384 + i*512
  const int rdB = 8192 + (wcN + fr) * 32 + swz;   // + buf*16384 + j*512

  const int srow = lane >> 2;
  const int sk = ((lane & 3) ^ ((lane >> 3) & 3)) * 8;
  const uint16_t* gA0 = A + (size_t)(m0 + wave * 16 + srow) * 8192 + kv0 + sk;
  const uint16_t* gA1 = gA0 + (size_t)128 * 8192;
  const uint16_t* gB0 = Bt + (size_t)(n0 + wave * 16 + srow) * 8192 + kv0 + sk;
  const uint16_t* gB1 = gB0 + (size_t)128 * 8192;

  f32x4 acc[8][4] = {};
  const int NT = 128;   // K = 4096

  // prologue: stage tiles 0,1,2 into ring slots 0,1,2
  for (int s = 0; s < 3; ++s) {
    const int ko = s * 32;
    uint16_t* d = SH + s * 16384 + wave * 512;
    gload16(gA0 + ko, d);
    gload16(gA1 + ko, d + 4096);
    gload16(gB0 + ko, d + 8192);
    gload16(gB1 + ko, d + 12288);
  }
  asm volatile("s_waitcnt vmcnt(8)" ::: "memory");   // tile 0 landed
  __builtin_amdgcn_sched_barrier(0);
  __builtin_amdgcn_s_barrier();
  __builtin_amdgcn_sched_barrier(0);

#define PV_TILE(T_, B_, BS_)                                                   \
  do {                                                                         \
    const uint16_t* bA_ = SH + (B_) * 16384;                                   \
    const int kp_ = (((T_) + 3) & (NT - 1)) * 32;                              \
    uint16_t* sd_ = SH + (BS_) * 16384 + wave * 512;                           \
    gload16(gA0 + kp_, sd_);                                                   \
    gload16(gA1 + kp_, sd_ + 4096);                                            \
    gload16(gB0 + kp_, sd_ + 8192);                                            \
    gload16(gB1 + kp_, sd_ + 12288);                                           \
    bf16x8 aq[8], bq[4];                                                       \
    _Pragma("unroll") for (int j = 0; j < 4; ++j)                              \
        bq[j] = *(const bf16x8*)(bA_ + rdB + j * 512);                         \
    _Pragma("unroll") for (int i = 0; i < 8; ++i)                              \
        aq[i] = *(const bf16x8*)(bA_ + rdA + i * 512);                         \
    __builtin_amdgcn_s_setprio(1);                                             \
    _Pragma("unroll") for (int i = 0; i < 8; ++i)                              \
      _Pragma("unroll") for (int j = 0; j < 4; ++j)                            \
          acc[i][j] = __builtin_amdgcn_mfma_f32_16x16x32_bf16(                 \
              aq[i], bq[j], acc[i][j], 0, 0, 0);                               \
    __builtin_amdgcn_s_setprio(0);                                             \
    asm volatile("s_waitcnt vmcnt(8)" ::: "memory");                           \
    __builtin_amdgcn_sched_barrier(0);                                         \
    __builtin_amdgcn_s_barrier();                                              \
    __builtin_amdgcn_sched_barrier(0);                                         \
  } while (0)

  for (int t0 = 0; t0 < NT; t0 += 4) {
    PV_TILE(t0 + 0, 0, 3);
    PV_TILE(t0 + 1, 1, 0);
    PV_TILE(t0 + 2, 2, 1);
    PV_TILE(t0 + 3, 3, 2);
  }
#undef PV_TILE

  // drain wrapped tail stages before reusing LDS as the epilogue arena
  asm volatile("s_waitcnt vmcnt(0)" ::: "memory");
  __builtin_amdgcn_sched_barrier(0);
  __builtin_amdgcn_s_barrier();
  __builtin_amdgcn_sched_barrier(0);

  // epilogue: raw bf16 partial, per-wave [16][72] arena bounce, 16B stores
  uint16_t* dst = kh ? P1 : P0;
  uint16_t* ar = SH + wave * 2048;
  const int lrow = lane >> 3;
  const int nc = (lane & 7) * 8;
#pragma unroll
  for (int i = 0; i < 8; ++i) {
#pragma unroll
    for (int j = 0; j < 4; ++j)
#pragma unroll
      for (int r = 0; r < 4; ++r)
        ar[(rg * 4 + r) * 72 + j * 16 + fr] = f2bf(acc[i][j][r]);
#pragma unroll
    for (int rr = 0; rr < 2; ++rr) {
      const size_t base = (size_t)(m0 + wrM + i * 16 + rr * 8 + lrow) * 2048 + n0 + wcN + nc;
      bf16x8 v = *(const bf16x8*)(ar + (rr * 8 + lrow) * 72 + nc);
      *(bf16x8*)(dst + base) = v;
    }
  }
}

// ---------------------------------------------------------------------------
// k_final: y = (out2g@WoT^T + bo) * x, fp32 out. 128x128, K=2048, ring-4.
// Launched per stripe (A/x/o32 pointers pre-offset; grid.y = 32).
// ---------------------------------------------------------------------------
__global__ __launch_bounds__(256, 2) void k_final(
    const uint16_t* __restrict__ A,
    const uint16_t* __restrict__ Bt, EpiParams p) {
  __shared__ __align__(16) uint16_t SH[32768];

  const int tid = threadIdx.x;
  const int lane = tid & 63;
  const int wave = tid >> 6;
  const int wr = (wave >> 1) * 64;
  const int wc = (wave & 1) * 64;
  const int m0 = blockIdx.y * 128;
  const int n0 = blockIdx.x * 128;
  const int lda = 2048, ldb = 2048;
  const int NT = 64;   // K=2048

  f32x4 acc[4][4] = {};

  const int fr = lane & 15;
  const int rg = lane >> 4;
  const int swz = (rg ^ ((fr >> 1) & 3)) * 8;
  const int rdA = (wr + fr) * 32 + swz;
  const int rdB = 4096 + (wc + fr) * 32 + swz;

  const int srow = lane >> 2;
  const int sk = ((lane & 3) ^ ((lane >> 3) & 3)) * 8;
  const uint16_t* gA0 = A + (size_t)(m0 + wave * 16 + srow) * lda + sk;
  const uint16_t* gA1 = gA0 + (size_t)64 * lda;
  const uint16_t* gB0 = Bt + (size_t)(n0 + wave * 16 + srow) * ldb + sk;
  const uint16_t* gB1 = gB0 + (size_t)64 * ldb;

  RING_LOOP128();

#pragma unroll
  for (int i = 0; i < 4; ++i) {
#pragma unroll
    for (int j = 0; j < 4; ++j) {
      const int row = m0 + wr + i * 16 + rg * 4;
      const int col = n0 + wc + j * 16 + fr;
      const float bc = p.bias[col];
#pragma unroll
      for (int r = 0; r < 4; ++r) {
        size_t idx = (size_t)(row + r) * 1024 + col;
        p.o32[idx] = (acc[i][j][r] + bc) * p.x[idx];
      }
    }
  }
}

// ---------------- launch ----------------

extern "C" void kernel_launch(void* const* d_in, const int* in_sizes, int n_in,
                              void* d_out, int out_size, void* d_ws, size_t ws_size,
                              hipStream_t stream) {
  const float* x        = (const float*)d_in[0];
  const float* W_hidden = (const float*)d_in[1];
  const float* b_hidden = (const float*)d_in[2];
  const float* W_qk     = (const float*)d_in[3];
  const float* b_qk     = (const float*)d_in[4];
  const float* gamma    = (const float*)d_in[5];
  const float* beta     = (const float*)d_in[6];
  const float* W_out    = (const float*)d_in[7];
  const float* b_out    = (const float*)d_in[8];
  float* out = (float*)d_out;

  char* base = (char*)d_ws;
  uint16_t* xb    = (uint16_t*)(base);                         // 16 MB  [8192][1024]
  uint16_t* WhT   = (uint16_t*)(base + (16ull << 20));         //  8 MB  [4096][1024]
  uint16_t* WqkT  = (uint16_t*)(base + (24ull << 20));         // .5 MB  [256][1024]
  uint16_t* attnB = (uint16_t*)(base);                         // 64 MB  [4096][8192]
  char* tail = base + (64ull << 20);
  uint16_t* WoT   = (uint16_t*)(tail);                         //  4 MB  [1024][2048]
  uint16_t* q     = (uint16_t*)(tail + (4ull << 20));          //  4 MB  [8192][256]
  uint16_t* kk    = (uint16_t*)(tail + (8ull << 20));          //  4 MB
  uint16_t* vT    = (uint16_t*)(tail + (12ull << 20));         // 32 MB  [2048][8192]
  uint16_t* gate  = (uint16_t*)(tail + (44ull << 20));         // 32 MB  [8192][2048]
  uint16_t* out2g = (uint16_t*)(tail + (76ull << 20));         // 32 MB  [8192][2048]
  (void)in_sizes; (void)n_in; (void)out_size; (void)ws_size;

  const size_t PH = 4096ull * 2048;   // elems per partial/stripe-half

  // prep
  cast_to_bf16<<<(8192 * 1024 / 4) / 256, 256, 0, stream>>>(x, xb, 8192 * 1024 / 4);
  transpose_cast_pad<<<dim3(4096 / 32, 1024 / 32), dim3(32, 8), 0, stream>>>(W_hidden, WhT, 1024, 4096, 4096);
  transpose_cast_pad<<<dim3(256 / 32, 1024 / 32), dim3(32, 8), 0, stream>>>(W_qk, WqkT, 1024, 200, 256);
  transpose_cast_pad<<<dim3(1024 / 32, 2048 / 32), dim3(32, 8), 0, stream>>>(W_out, WoT, 2048, 1024, 1024);

  // fused hid + qk   (N = 4096 + 256 = 4352)
  {
    EpiParams p{};
    p.bias = b_hidden; p.bias2 = b_qk;
    p.g0 = gamma; p.b0 = beta; p.g1 = gamma + 200; p.b1 = beta + 200;
    p.o16a = vT; p.o16b = gate; p.oq = q; p.ok = kk;
    k_hidqk<<<dim3(34, 64), 256, 0, stream>>>(xb, WhT, p);
  }

  // per stripe s: attn -> split-K pv (partials into out2g halves, ping-pong)
  //               -> k_sum (in-place, *gate) -> k_final (rows of stripe)
  for (int s = 0; s < 2; ++s) {
    k_attn<<<dim3(64, 32), 256, 0, stream>>>(q + (size_t)s * 4096 * 256, kk, attnB);

    uint16_t* Pa = out2g + (size_t)s * PH;         // kh=0 partial = final home
    uint16_t* Pb = out2g + (size_t)(1 - s) * PH;   // kh=1 partial = scratch
    k_pv<<<dim3(256), 512, 0, stream>>>(attnB, vT, Pa, Pb);

    k_sum<<<dim3((int)(PH / 8 / 256)), 256, 0, stream>>>(
        Pa, Pb, gate + (size_t)s * PH, (int)(PH / 8));

    EpiParams p{};
    p.bias = b_out;
    p.x = x + (size_t)s * 4096 * 1024;
    p.o32 = out + (size_t)s * 4096 * 1024;
    k_final<<<dim3(8, 32), 256, 0, stream>>>(Pa, WoT, p);
  }
}

// Round 7
// 607.245 us; speedup vs baseline: 1.4550x; 1.0761x over previous
//
#include <hip/hip_runtime.h>
#include <stdint.h>

// ---------------------------------------------------------------------------
// GAU forward on MI355X (gfx950), bf16 MFMA everywhere.
//   hid|qk = silu(x@[Wh|Wqk]+b) -> vT [2048][8192], gate [8192][2048],
//                                  q,k bf16 [8192][256] (cols 200..255 zero)
//   attn = relu(q@kT / 32)^2    bf16 (full [8192][8192]; ws>=236MB proven by R9)
//   out2 = (attn@v) * gate      bf16 [8192][2048]
//   y    = (out2@Wo + bo) * x   fp32 [8192][1024]
//
// R14 = R13 resubmitted verbatim (R13 bench was an infra/container failure;
// audit found no hang/fault path: uniform barriers, sound ring invariant,
// in-bounds LDS/global, 128KB static LDS already proven in R8/R9).
//
// R13: unified 256x256 8-wave engine with cross-tile REGISTER double-buffer:
// at tile t, stage slot t+3, ds_read frags(t+1) into the alternate reg set,
// MFMA tile t from the current set (no dependency -> LDS burst overlaps MFMA
// burst; removes the measured ~840 cyc/tile post-barrier read stall).
// vmcnt(4): slot t+2 resident at end of tile t (frags(t+2) read during t+1);
// slot t+3's loads get ~2 tiles of flight (R10's vmcnt(3) regression was a
// 1-tile window < 900-cyc HBM latency). Engine used by k_pv (fullM, K=8192,
// 256 blocks), k_hidqk (17x32 grid; 8-wave vT/gate/qk epilogues; was 126 us
// at 24.6% MfmaUtil on the 128^2 engine), k_attn (32x32 grid). k_final keeps
// the 128^2 engine. fullM restored (R12's forced striping+k_sum was -83 us);
// striped split-K path kept as fallback only.
// ---------------------------------------------------------------------------

typedef __bf16 bf16x8 __attribute__((ext_vector_type(8)));
typedef float f32x4 __attribute__((ext_vector_type(4)));

__device__ __forceinline__ uint16_t f2bf(float f) {
  uint32_t u = __builtin_bit_cast(uint32_t, f);
  u += 0x7fffu + ((u >> 16) & 1u);   // RNE; inputs are finite
  return (uint16_t)(u >> 16);
}
__device__ __forceinline__ float silu_f(float s) {
  return s / (1.f + __expf(-s));
}

__device__ __forceinline__ void gload16(const void* g, void* l) {
  __builtin_amdgcn_global_load_lds(
      (__attribute__((address_space(1))) void*)const_cast<void*>(g),
      (__attribute__((address_space(3))) void*)l, 16, 0, 0);
}

// ---------------- elementwise prep ----------------

__global__ void cast_to_bf16(const float* __restrict__ in, uint16_t* __restrict__ out, int n4) {
  int i = blockIdx.x * blockDim.x + threadIdx.x;
  if (i < n4) {
    float4 f = ((const float4*)in)[i];
    ushort4 o;
    o.x = f2bf(f.x); o.y = f2bf(f.y); o.z = f2bf(f.z); o.w = f2bf(f.w);
    ((ushort4*)out)[i] = o;
  }
}

// out[c][r] = (c < C) ? (bf16)in[r][c] : 0   ; out is [Cp][R]
__global__ void transpose_cast_pad(const float* __restrict__ in, uint16_t* __restrict__ out,
                                   int R, int C, int Cp) {
  __shared__ float tile[32][33];
  int cb = blockIdx.x * 32;
  int rb = blockIdx.y * 32;
  int tx = threadIdx.x;
  int ty = threadIdx.y;
#pragma unroll
  for (int i = 0; i < 4; ++i) {
    int r = rb + ty + i * 8;
    int c = cb + tx;
    tile[ty + i * 8][tx] = (c < C) ? in[(size_t)r * C + c] : 0.f;
  }
  __syncthreads();
#pragma unroll
  for (int i = 0; i < 4; ++i) {
    int c = cb + ty + i * 8;
    if (c < Cp) out[(size_t)c * R + rb + tx] = f2bf(tile[tx][ty + i * 8]);
  }
}

// k_sum: P0 = (P0 + P1) * gate, elementwise bf16x8, in-place (striped path).
__global__ void k_sum(uint16_t* __restrict__ P0, const uint16_t* __restrict__ P1,
                      const uint16_t* __restrict__ g, int n8) {
  int i = blockIdx.x * blockDim.x + threadIdx.x;
  if (i < n8) {
    bf16x8 a = ((const bf16x8*)P0)[i];
    bf16x8 b = ((const bf16x8*)P1)[i];
    bf16x8 gg = ((const bf16x8*)g)[i];
    bf16x8 o;
#pragma unroll
    for (int e = 0; e < 8; ++e)
      o[e] = (__bf16)(((float)a[e] + (float)b[e]) * (float)gg[e]);
    ((bf16x8*)P0)[i] = o;
  }
}

// ---------------- params ----------------

struct EpiParams {
  const float* bias;
  const float* bias2;
  const float* g0;
  const float* b0;
  const float* g1;
  const float* b1;
  const uint16_t* gate;
  const float* x;
  uint16_t* o16a;
  uint16_t* o16b;
  uint16_t* oq;
  uint16_t* ok;
  float* o32;
};

// ---------------------------------------------------------------------------
// 256x256 8-wave reg-dbuf engine. Ring-4 slots of 32 KB (A 16K | B 16K),
// SH = uint16_t[65536] (128 KB). Requires in scope: NT (pow2), wave, rdA,
// rdB, gA0,gA1,gB0,gB1 (inverse-swizzled stage pointers), acc[8][4],
// fa0[8],fb0[4],fa1[8],fb1[4].
// Tile t: stage slot (t+3)&3, read frags(t+1) from slot (t+1)&3 into the
// NEXT reg set, MFMA CURRENT set, vmcnt(4), barrier.
// Residency: vmcnt(4) at end of tile t completes slot t+2 (outstanding =
// slots t+2,t+3 = 8 loads/wave). Slot t+1 resident at START of tile t.
// Last tile's next-set reads are dead (wrapped data, never consumed).
// ---------------------------------------------------------------------------
#define ET(T_, WS_, RS_, CA_, CB_, NA_, NB_)                                   \
  do {                                                                         \
    const int kp_ = (((T_) + 3) & (NT - 1)) * 32;                              \
    uint16_t* sd_ = SH + (WS_) * 16384 + wave * 512;                           \
    gload16(gA0 + kp_, sd_);                                                   \
    gload16(gA1 + kp_, sd_ + 4096);                                            \
    gload16(gB0 + kp_, sd_ + 8192);                                            \
    gload16(gB1 + kp_, sd_ + 12288);                                           \
    const uint16_t* rb_ = SH + (RS_) * 16384;                                  \
    _Pragma("unroll") for (int j_ = 0; j_ < 4; ++j_)                           \
        NB_[j_] = *(const bf16x8*)(rb_ + rdB + j_ * 512);                      \
    _Pragma("unroll") for (int i_ = 0; i_ < 8; ++i_)                           \
        NA_[i_] = *(const bf16x8*)(rb_ + rdA + i_ * 512);                      \
    __builtin_amdgcn_sched_barrier(0);                                         \
    __builtin_amdgcn_s_setprio(1);                                             \
    _Pragma("unroll") for (int i_ = 0; i_ < 8; ++i_)                           \
      _Pragma("unroll") for (int j_ = 0; j_ < 4; ++j_)                         \
          acc[i_][j_] = __builtin_amdgcn_mfma_f32_16x16x32_bf16(               \
              CA_[i_], CB_[j_], acc[i_][j_], 0, 0, 0);                         \
    __builtin_amdgcn_s_setprio(0);                                             \
    asm volatile("s_waitcnt vmcnt(4)" ::: "memory");                           \
    __builtin_amdgcn_sched_barrier(0);                                         \
    __builtin_amdgcn_s_barrier();                                              \
    __builtin_amdgcn_sched_barrier(0);                                         \
  } while (0)

#define ENGINE256()                                                            \
  do {                                                                         \
    _Pragma("unroll") for (int s_ = 0; s_ < 3; ++s_) {                         \
      uint16_t* d_ = SH + s_ * 16384 + wave * 512;                             \
      gload16(gA0 + s_ * 32, d_);                                              \
      gload16(gA1 + s_ * 32, d_ + 4096);                                       \
      gload16(gB0 + s_ * 32, d_ + 8192);                                       \
      gload16(gB1 + s_ * 32, d_ + 12288);                                      \
    }                                                                          \
    asm volatile("s_waitcnt vmcnt(4)" ::: "memory");                           \
    __builtin_amdgcn_sched_barrier(0);                                         \
    __builtin_amdgcn_s_barrier();                                              \
    __builtin_amdgcn_sched_barrier(0);                                         \
    _Pragma("unroll") for (int j_ = 0; j_ < 4; ++j_)                           \
        fb0[j_] = *(const bf16x8*)(SH + rdB + j_ * 512);                       \
    _Pragma("unroll") for (int i_ = 0; i_ < 8; ++i_)                           \
        fa0[i_] = *(const bf16x8*)(SH + rdA + i_ * 512);                       \
    for (int t0_ = 0; t0_ < NT; t0_ += 4) {                                    \
      ET(t0_ + 0, 3, 1, fa0, fb0, fa1, fb1);                                   \
      ET(t0_ + 1, 0, 2, fa1, fb1, fa0, fb0);                                   \
      ET(t0_ + 2, 1, 3, fa0, fb0, fa1, fb1);                                   \
      ET(t0_ + 3, 2, 0, fa1, fb1, fa0, fb0);                                   \
    }                                                                          \
    asm volatile("s_waitcnt vmcnt(0)" ::: "memory");                           \
    __builtin_amdgcn_sched_barrier(0);                                         \
    __syncthreads();                                                           \
  } while (0)

// 128x128 4-wave ring-4 engine (k_final only; proven R9 structure).
#define TILE128(T_, B_, BS_)                                                   \
  do {                                                                         \
    const uint16_t* base_ = SH + (B_) * 8192;                                  \
    const int kp_ = (((T_) + 3) & (NT - 1)) * 32;                              \
    uint16_t* sd_ = SH + (BS_) * 8192 + wave * 512;                            \
    gload16(gA0 + kp_, sd_);                                                   \
    gload16(gA1 + kp_, sd_ + 2048);                                            \
    gload16(gB0 + kp_, sd_ + 4096);                                            \
    gload16(gB1 + kp_, sd_ + 6144);                                            \
    bf16x8 a_[4], b_[4];                                                       \
    _Pragma("unroll") for (int j_ = 0; j_ < 4; ++j_)                           \
        b_[j_] = *(const bf16x8*)(base_ + rdB + j_ * 512);                     \
    _Pragma("unroll") for (int i_ = 0; i_ < 4; ++i_)                           \
        a_[i_] = *(const bf16x8*)(base_ + rdA + i_ * 512);                     \
    __builtin_amdgcn_s_setprio(1);                                             \
    _Pragma("unroll") for (int i_ = 0; i_ < 4; ++i_)                           \
      _Pragma("unroll") for (int j_ = 0; j_ < 4; ++j_)                         \
          acc[i_][j_] = __builtin_amdgcn_mfma_f32_16x16x32_bf16(               \
              a_[i_], b_[j_], acc[i_][j_], 0, 0, 0);                           \
    __builtin_amdgcn_s_setprio(0);                                             \
    asm volatile("s_waitcnt vmcnt(8)" ::: "memory");                           \
    __builtin_amdgcn_sched_barrier(0);                                         \
    __builtin_amdgcn_s_barrier();                                              \
    __builtin_amdgcn_sched_barrier(0);                                         \
  } while (0)

#define RING_LOOP128()                                                         \
  do {                                                                         \
    _Pragma("unroll") for (int s_ = 0; s_ < 3; ++s_) {                         \
      uint16_t* d_ = SH + s_ * 8192 + wave * 512;                              \
      gload16(gA0 + s_ * 32, d_);                                              \
      gload16(gA1 + s_ * 32, d_ + 2048);                                       \
      gload16(gB0 + s_ * 32, d_ + 4096);                                       \
      gload16(gB1 + s_ * 32, d_ + 6144);                                       \
    }                                                                          \
    asm volatile("s_waitcnt vmcnt(8)" ::: "memory");                           \
    __builtin_amdgcn_sched_barrier(0);                                         \
    __builtin_amdgcn_s_barrier();                                              \
    __builtin_amdgcn_sched_barrier(0);                                         \
    for (int t0_ = 0; t0_ < NT; t0_ += 4) {                                    \
      TILE128(t0_ + 0, 0, 3);                                                  \
      TILE128(t0_ + 1, 1, 0);                                                  \
      TILE128(t0_ + 2, 2, 1);                                                  \
      TILE128(t0_ + 3, 3, 2);                                                  \
    }                                                                          \
    asm volatile("s_waitcnt vmcnt(0)" ::: "memory");                           \
    __builtin_amdgcn_sched_barrier(0);                                         \
    __syncthreads();                                                           \
  } while (0)

// ---------------------------------------------------------------------------
// k_hidqk: C = xb[8192,1024] @ [WhT;WqkT][4352,1024]^T, 256x256 tile,
// 8 waves (wave tile 128x64). Grid 17 x 32. Per-block epilogue cases by n0:
// blocks 0..7 -> vT (transposed), 8..15 -> gate, 16 -> q,k.
// ---------------------------------------------------------------------------
__global__ __launch_bounds__(512, 2) void k_hidqk(
    const uint16_t* __restrict__ A, const uint16_t* __restrict__ Bt, EpiParams p) {
  __shared__ __align__(16) uint16_t SH[65536];   // 128 KB ring

  const int tid = threadIdx.x;
  const int lane = tid & 63;
  const int wave = tid >> 6;
  const int wrM = (wave >> 2) * 128;
  const int wcN = (wave & 3) * 64;
  const int m0 = blockIdx.y * 256;
  const int n0 = blockIdx.x * 256;
  const int lda = 1024, ldb = 1024;
  const int NT = 32;   // K=1024

  f32x4 acc[8][4] = {};

  const int fr = lane & 15;
  const int rg = lane >> 4;
  const int swz = (rg ^ ((fr >> 1) & 3)) * 8;
  const int rdA = (wrM + fr) * 32 + swz;
  const int rdB = 8192 + (wcN + fr) * 32 + swz;

  const int srow = lane >> 2;
  const int sk = ((lane & 3) ^ ((lane >> 3) & 3)) * 8;
  const uint16_t* gA0 = A + (size_t)(m0 + wave * 16 + srow) * lda + sk;
  const uint16_t* gA1 = gA0 + (size_t)128 * lda;
  const uint16_t* gB0 = Bt + (size_t)(n0 + wave * 16 + srow) * ldb + sk;
  const uint16_t* gB1 = gB0 + (size_t)128 * ldb;

  bf16x8 fa0[8], fb0[4], fa1[8], fb1[4];
  ENGINE256();

  // C/D layout: col = lane&15, row = rg*4 + reg   [m89-verified]
  if (n0 < 2048) {
    // vT transposed store. Per j: arena [16 n][128 m + 8 pad] stride 136.
    uint16_t* ar = SH + wave * 2304;
#pragma unroll
    for (int j = 0; j < 4; ++j) {
      const float bc = p.bias[n0 + wcN + j * 16 + fr];
#pragma unroll
      for (int i = 0; i < 8; ++i)
#pragma unroll
        for (int r = 0; r < 4; ++r)
          ar[fr * 136 + i * 16 + rg * 4 + r] = f2bf(silu_f(acc[i][j][r] + bc));
      const int mc = (lane & 15) * 8;
#pragma unroll
      for (int it = 0; it < 4; ++it) {
        const int nrow = it * 4 + (lane >> 4);
        bf16x8 v = *(const bf16x8*)(ar + nrow * 136 + mc);
        *(bf16x8*)(p.o16a + (size_t)(n0 + wcN + j * 16 + nrow) * 8192 + m0 + wrM + mc) = v;
      }
    }
  } else if (n0 < 4096) {
    // gate. Per i: arena [16 m][64 n + pad] stride 72.
    uint16_t* ar = SH + wave * 2048;
    const int lrow = lane >> 3;
    const int nc = (lane & 7) * 8;
    float bc[4];
#pragma unroll
    for (int j = 0; j < 4; ++j) bc[j] = p.bias[n0 + wcN + j * 16 + fr];
#pragma unroll
    for (int i = 0; i < 8; ++i) {
#pragma unroll
      for (int j = 0; j < 4; ++j)
#pragma unroll
        for (int r = 0; r < 4; ++r)
          ar[(rg * 4 + r) * 72 + j * 16 + fr] = f2bf(silu_f(acc[i][j][r] + bc[j]));
#pragma unroll
      for (int rr = 0; rr < 2; ++rr) {
        bf16x8 v = *(const bf16x8*)(ar + (rr * 8 + lrow) * 72 + nc);
        *(bf16x8*)(p.o16b + (size_t)(m0 + wrM + i * 16 + rr * 8 + lrow) * 2048 + (n0 - 2048) + wcN + nc) = v;
      }
    }
  } else {
    // q,k: stride 256, cols 200..255 forced zero. n0==4096 -> qc = wcN+j*16+fr.
#pragma unroll
    for (int i = 0; i < 8; ++i) {
#pragma unroll
      for (int j = 0; j < 4; ++j) {
        const int row = m0 + wrM + i * 16 + rg * 4;
        const int qc = wcN + j * 16 + fr;   // 0..255
#pragma unroll
        for (int r = 0; r < 4; ++r) {
          float qv = 0.f, kv = 0.f;
          if (qc < 200) {
            float s = silu_f(acc[i][j][r] + p.bias2[qc]);
            qv = s * p.g0[qc] + p.b0[qc];
            kv = s * p.g1[qc] + p.b1[qc];
          }
          p.oq[(size_t)(row + r) * 256 + qc] = f2bf(qv);
          p.ok[(size_t)(row + r) * 256 + qc] = f2bf(kv);
        }
      }
    }
  }
}

// ---------------------------------------------------------------------------
// k_attn: attn = relu(q@kT/32)^2, K=256 (padded), 256x256 tile, 8 waves.
// Grid (32, mtiles). Epilogue: per i, [16][72] arena, 2x16B stores.
// ---------------------------------------------------------------------------
__global__ __launch_bounds__(512, 2) void k_attn(
    const uint16_t* __restrict__ Q,
    const uint16_t* __restrict__ Kt,
    uint16_t* __restrict__ attn) {
  __shared__ __align__(16) uint16_t SH[65536];

  const int tid = threadIdx.x;
  const int lane = tid & 63;
  const int wave = tid >> 6;
  const int wrM = (wave >> 2) * 128;
  const int wcN = (wave & 3) * 64;
  const int m0 = blockIdx.y * 256;
  const int n0 = blockIdx.x * 256;
  const int lda = 256, ldb = 256;
  const int NT = 8;   // K=256

  f32x4 acc[8][4] = {};

  const int fr = lane & 15;
  const int rg = lane >> 4;
  const int swz = (rg ^ ((fr >> 1) & 3)) * 8;
  const int rdA = (wrM + fr) * 32 + swz;
  const int rdB = 8192 + (wcN + fr) * 32 + swz;

  const int srow = lane >> 2;
  const int sk = ((lane & 3) ^ ((lane >> 3) & 3)) * 8;
  const uint16_t* gA0 = Q + (size_t)(m0 + wave * 16 + srow) * lda + sk;
  const uint16_t* gA1 = gA0 + (size_t)128 * lda;
  const uint16_t* gB0 = Kt + (size_t)(n0 + wave * 16 + srow) * ldb + sk;
  const uint16_t* gB1 = gB0 + (size_t)128 * ldb;

  bf16x8 fa0[8], fb0[4], fa1[8], fb1[4];
  ENGINE256();

  uint16_t* ar = SH + wave * 2048;
  const int row = lane >> 2;
  const int c0 = (lane & 3) * 16;
#pragma unroll
  for (int i = 0; i < 8; ++i) {
#pragma unroll
    for (int j = 0; j < 4; ++j)
#pragma unroll
      for (int r = 0; r < 4; ++r) {
        float s = fmaxf(acc[i][j][r] * 0.03125f, 0.f);
        ar[(rg * 4 + r) * 72 + j * 16 + fr] = f2bf(s * s);
      }
    bf16x8 v0 = *(const bf16x8*)(ar + row * 72 + c0);
    bf16x8 v1 = *(const bf16x8*)(ar + row * 72 + c0 + 8);
    uint16_t* dst = attn + (size_t)(m0 + wrM + i * 16 + row) * 8192 + (n0 + wcN + c0);
    *(bf16x8*)(dst) = v0;
    *(bf16x8*)(dst + 8) = v1;
  }
}

// ---------------------------------------------------------------------------
// k_pv: out2 = (attn@v)[*gate]. 256x256 tile, 8 waves, reg-dbuf engine.
// split=0 (fullM): grid 256 = {bx=(id>>3)&7, by=(id&7)+8*(id>>6)}, K=8192,
//   gated store to P0.
// split=1 (striped): grid 256 = {bx=id&7, kh=(id>>3)&1, by=id>>4}, K=4096,
//   raw partial to P0/P1 (k_sum applies gate).
// ---------------------------------------------------------------------------
__global__ __launch_bounds__(512, 2) void k_pv(
    const uint16_t* __restrict__ A,
    const uint16_t* __restrict__ Bt,
    uint16_t* __restrict__ P0,
    uint16_t* __restrict__ P1,
    const uint16_t* __restrict__ gate,
    int split) {
  __shared__ __align__(16) uint16_t SH[65536];

  const int id = blockIdx.x;
  int bx, by, kv0, NT;
  uint16_t* dst;
  if (split) {
    bx = id & 7;
    by = id >> 4;
    kv0 = ((id >> 3) & 1) * 4096;
    NT = 128;
    dst = ((id >> 3) & 1) ? P1 : P0;
  } else {
    bx = (id >> 3) & 7;
    by = (id & 7) + 8 * (id >> 6);
    kv0 = 0;
    NT = 256;
    dst = P0;
  }
  const int m0 = by * 256;
  const int n0 = bx * 256;

  const int tid = threadIdx.x;
  const int lane = tid & 63;
  const int wave = tid >> 6;
  const int wrM = (wave >> 2) * 128;
  const int wcN = (wave & 3) * 64;

  const int fr = lane & 15;
  const int rg = lane >> 4;
  const int swz = (rg ^ ((fr >> 1) & 3)) * 8;
  const int rdA = (wrM + fr) * 32 + swz;
  const int rdB = 8192 + (wcN + fr) * 32 + swz;

  const int srow = lane >> 2;
  const int sk = ((lane & 3) ^ ((lane >> 3) & 3)) * 8;
  const uint16_t* gA0 = A + (size_t)(m0 + wave * 16 + srow) * 8192 + kv0 + sk;
  const uint16_t* gA1 = gA0 + (size_t)128 * 8192;
  const uint16_t* gB0 = Bt + (size_t)(n0 + wave * 16 + srow) * 8192 + kv0 + sk;
  const uint16_t* gB1 = gB0 + (size_t)128 * 8192;

  f32x4 acc[8][4] = {};
  bf16x8 fa0[8], fb0[4], fa1[8], fb1[4];
  ENGINE256();

  // epilogue: per-wave [16][72] arena bounce, 16B stores (gated if fullM)
  uint16_t* ar = SH + wave * 2048;
  const int lrow = lane >> 3;
  const int nc = (lane & 7) * 8;
#pragma unroll
  for (int i = 0; i < 8; ++i) {
#pragma unroll
    for (int j = 0; j < 4; ++j)
#pragma unroll
      for (int r = 0; r < 4; ++r)
        ar[(rg * 4 + r) * 72 + j * 16 + fr] = f2bf(acc[i][j][r]);
#pragma unroll
    for (int rr = 0; rr < 2; ++rr) {
      const size_t base = (size_t)(m0 + wrM + i * 16 + rr * 8 + lrow) * 2048 + n0 + wcN + nc;
      bf16x8 v = *(const bf16x8*)(ar + (rr * 8 + lrow) * 72 + nc);
      if (gate) {
        bf16x8 g = *(const bf16x8*)(gate + base);
        bf16x8 o;
#pragma unroll
        for (int e = 0; e < 8; ++e) o[e] = (__bf16)((float)v[e] * (float)g[e]);
        *(bf16x8*)(dst + base) = o;
      } else {
        *(bf16x8*)(dst + base) = v;
      }
    }
  }
}

// ---------------------------------------------------------------------------
// k_final: y = (out2g@WoT^T + bo) * x, fp32 out. 128x128, K=2048, ring-4.
// ---------------------------------------------------------------------------
__global__ __launch_bounds__(256, 2) void k_final(
    const uint16_t* __restrict__ A,
    const uint16_t* __restrict__ Bt, EpiParams p) {
  __shared__ __align__(16) uint16_t SH[32768];

  const int tid = threadIdx.x;
  const int lane = tid & 63;
  const int wave = tid >> 6;
  const int wr = (wave >> 1) * 64;
  const int wc = (wave & 1) * 64;
  const int m0 = blockIdx.y * 128;
  const int n0 = blockIdx.x * 128;
  const int lda = 2048, ldb = 2048;
  const int NT = 64;   // K=2048

  f32x4 acc[4][4] = {};

  const int fr = lane & 15;
  const int rg = lane >> 4;
  const int swz = (rg ^ ((fr >> 1) & 3)) * 8;
  const int rdA = (wr + fr) * 32 + swz;
  const int rdB = 4096 + (wc + fr) * 32 + swz;

  const int srow = lane >> 2;
  const int sk = ((lane & 3) ^ ((lane >> 3) & 3)) * 8;
  const uint16_t* gA0 = A + (size_t)(m0 + wave * 16 + srow) * lda + sk;
  const uint16_t* gA1 = gA0 + (size_t)64 * lda;
  const uint16_t* gB0 = Bt + (size_t)(n0 + wave * 16 + srow) * ldb + sk;
  const uint16_t* gB1 = gB0 + (size_t)64 * ldb;

  RING_LOOP128();

#pragma unroll
  for (int i = 0; i < 4; ++i) {
#pragma unroll
    for (int j = 0; j < 4; ++j) {
      const int row = m0 + wr + i * 16 + rg * 4;
      const int col = n0 + wc + j * 16 + fr;
      const float bc = p.bias[col];
#pragma unroll
      for (int r = 0; r < 4; ++r) {
        size_t idx = (size_t)(row + r) * 1024 + col;
        p.o32[idx] = (acc[i][j][r] + bc) * p.x[idx];
      }
    }
  }
}

// ---------------- launch ----------------

extern "C" void kernel_launch(void* const* d_in, const int* in_sizes, int n_in,
                              void* d_out, int out_size, void* d_ws, size_t ws_size,
                              hipStream_t stream) {
  const float* x        = (const float*)d_in[0];
  const float* W_hidden = (const float*)d_in[1];
  const float* b_hidden = (const float*)d_in[2];
  const float* W_qk     = (const float*)d_in[3];
  const float* b_qk     = (const float*)d_in[4];
  const float* gamma    = (const float*)d_in[5];
  const float* beta     = (const float*)d_in[6];
  const float* W_out    = (const float*)d_in[7];
  const float* b_out    = (const float*)d_in[8];
  float* out = (float*)d_out;

  const bool fullM = ws_size >= (236ull << 20);
  const size_t region0 = fullM ? (128ull << 20) : (64ull << 20);

  char* base = (char*)d_ws;
  uint16_t* xb    = (uint16_t*)(base);                         // 16 MB  [8192][1024]
  uint16_t* WhT   = (uint16_t*)(base + (16ull << 20));         //  8 MB  [4096][1024]
  uint16_t* WqkT  = (uint16_t*)(base + (24ull << 20));         // .5 MB  [256][1024]
  uint16_t* attnB = (uint16_t*)(base);                         // 64/128 MB
  char* tail = base + region0;
  uint16_t* WoT   = (uint16_t*)(tail);                         //  4 MB  [1024][2048]
  uint16_t* q     = (uint16_t*)(tail + (4ull << 20));          //  4 MB  [8192][256]
  uint16_t* kk    = (uint16_t*)(tail + (8ull << 20));          //  4 MB
  uint16_t* vT    = (uint16_t*)(tail + (12ull << 20));         // 32 MB  [2048][8192]
  uint16_t* gate  = (uint16_t*)(tail + (44ull << 20));         // 32 MB  [8192][2048]
  uint16_t* out2g = (uint16_t*)(tail + (76ull << 20));         // 32 MB  [8192][2048]
  (void)in_sizes; (void)n_in; (void)out_size;

  // prep
  cast_to_bf16<<<(8192 * 1024 / 4) / 256, 256, 0, stream>>>(x, xb, 8192 * 1024 / 4);
  transpose_cast_pad<<<dim3(4096 / 32, 1024 / 32), dim3(32, 8), 0, stream>>>(W_hidden, WhT, 1024, 4096, 4096);
  transpose_cast_pad<<<dim3(256 / 32, 1024 / 32), dim3(32, 8), 0, stream>>>(W_qk, WqkT, 1024, 200, 256);
  transpose_cast_pad<<<dim3(1024 / 32, 2048 / 32), dim3(32, 8), 0, stream>>>(W_out, WoT, 2048, 1024, 1024);

  // fused hid + qk   (N = 4096 + 256 = 4352; blocks x: 0..7 vT, 8..15 gate, 16 qk)
  {
    EpiParams p{};
    p.bias = b_hidden; p.bias2 = b_qk;
    p.g0 = gamma; p.b0 = beta; p.g1 = gamma + 200; p.b1 = beta + 200;
    p.o16a = vT; p.o16b = gate; p.oq = q; p.ok = kk;
    k_hidqk<<<dim3(17, 32), 512, 0, stream>>>(xb, WhT, p);
  }

  if (fullM) {
    k_attn<<<dim3(32, 32), 512, 0, stream>>>(q, kk, attnB);
    k_pv<<<dim3(256), 512, 0, stream>>>(attnB, vT, out2g, nullptr, gate, 0);
    EpiParams p{};
    p.bias = b_out; p.x = x; p.o32 = out;
    k_final<<<dim3(8, 64), 256, 0, stream>>>(out2g, WoT, p);
  } else {
    const size_t PH = 4096ull * 2048;
    for (int s = 0; s < 2; ++s) {
      k_attn<<<dim3(32, 16), 512, 0, stream>>>(q + (size_t)s * 4096 * 256, kk, attnB);
      uint16_t* Pa = out2g + (size_t)s * PH;
      uint16_t* Pb = out2g + (size_t)(1 - s) * PH;
      k_pv<<<dim3(256), 512, 0, stream>>>(attnB, vT, Pa, Pb, nullptr, 1);
      k_sum<<<dim3((int)(PH / 8 / 256)), 256, 0, stream>>>(
          Pa, Pb, gate + (size_t)s * PH, (int)(PH / 8));
      EpiParams p{};
      p.bias = b_out;
      p.x = x + (size_t)s * 4096 * 1024;
      p.o32 = out + (size_t)s * 4096 * 1024;
      k_final<<<dim3(8, 32), 256, 0, stream>>>(Pa, WoT, p);
    }
  }
}